// Round 7
// baseline (51.209 us; speedup 1.0000x reference)
//
#include <hip/hip_runtime.h>
#include <hip/hip_bf16.h>

#define CRF_B 512
#define CRF_S 1024
#define CRF_L 64
#define CRF_BOS 61
#define CRF_EOS 62
#define CRF_NC 32                  // chunks per sequence
#define CRF_CK (CRF_S / CRF_NC)    // 32 steps per chunk
#define CRF_W 8                    // burn-in steps
#define GRP 16                     // batches per wave
#define PART_BLOCKS ((CRF_B / GRP) * CRF_NC)   // 1024
#define TS 4                       // time-steps per LDS tile

typedef __attribute__((ext_vector_type(8))) short short8;
typedef __attribute__((ext_vector_type(4))) float f32x4;
#define UNR _Pragma("unroll")

__device__ __forceinline__ unsigned short f2bf(float x) {
    union { __hip_bfloat16 h; unsigned short u; } cv;
    cv.h = __float2bfloat16(x);
    return cv.u;
}

// async global->LDS: dest = uniform base + lane*width (linear); src per-lane
__device__ __forceinline__ void gload_lds16(const float* g, float* l) {
    __builtin_amdgcn_global_load_lds(
        (const __attribute__((address_space(1))) unsigned int*)(const void*)g,
        (__attribute__((address_space(3))) unsigned int*)(void*)l, 16, 0, 0);
}
__device__ __forceinline__ void gload_lds4(const float* g, float* l) {
    __builtin_amdgcn_global_load_lds(
        (const __attribute__((address_space(1))) unsigned int*)(const void*)g,
        (__attribute__((address_space(3))) unsigned int*)(void*)l, 4, 0, 0);
}

// -------------------- gold scores (fused, atomic output) ----------------
__device__ __forceinline__ void gold_body(
    int b, int l,
    const float* __restrict__ em, const float* __restrict__ trans,
    const int* __restrict__ tags, const float* __restrict__ mask,
    float* __restrict__ out)
{
    const float* emb = em + (size_t)b * CRF_S * CRF_L;
    const int*   tg  = tags + (size_t)b * CRF_S;
    const float* mk  = mask + (size_t)b * CRF_S;

    float acc = 0.f, msum = 0.f;
    for (int t = l; t < CRF_S; t += 64) {
        float m = mk[t];
        msum += m;
        if (t >= 1) {
            int ct = tg[t];
            int pt = tg[t - 1];
            acc += (emb[(size_t)t * CRF_L + ct] + trans[pt * CRF_L + ct]) * m;
        }
    }
    UNR
    for (int off = 32; off; off >>= 1) {
        acc  += __shfl_xor(acc, off);
        msum += __shfl_xor(msum, off);
    }
    if (l == 0) {
        int t0 = tg[0];
        acc += trans[CRF_BOS * CRF_L + t0] + emb[t0];
        int last = (int)(msum + 0.5f) - 1;
        int lt = tg[last];
        acc += trans[lt * CRF_L + CRF_EOS];
        atomicAdd(&out[b], -acc);
    }
}

// -------------------- MFMA chunked log partition, LDS-staged ------------
// Per tile: 16 batches x 4 steps staged via 17 global_load_lds (each batch's
// 1KB slice = one fully-coalesced dwordx4 instr). Double-buffered; counted
// s_waitcnt vmcnt(17) keeps one tile always in flight. LDS 16B-granule XOR
// swizzle (slot16 = labgrp16 ^ batch) applied inversely on the global source,
// giving conflict-balanced ds_read_b128 on the read side.
__device__ __forceinline__ void part_body(
    int pb, int l,
    const float* __restrict__ em, const float* __restrict__ trans,
    const float* __restrict__ mask, float* __restrict__ out,
    float (* __restrict__ em_s)[GRP][TS][CRF_L],   // [2][16][4][64]
    float (* __restrict__ mk_s)[TS][GRP])          // [2][4][16]
{
    const int c   = pb & (CRF_NC - 1);
    const int grp = pb / CRF_NC;
    const int lj  = l & 15;
    const int g   = l >> 4;

    // Constant A-frags: kappa-permuted exp(trans) (C/D layout == B layout).
    short8 Af[4][2];
    UNR for (int mt = 0; mt < 4; ++mt)
      UNR for (int kc = 0; kc < 2; ++kc) {
        short8 f;
        UNR for (int e = 0; e < 8; ++e) {
            int L = kc * 32 + (e >> 2) * 16 + g * 4 + (e & 3);
            f[e] = (short)f2bf(__expf(trans[L * CRF_L + mt * 16 + lj]));
        }
        Af[mt][kc] = f;
      }

    const int b0 = grp * GRP;
    const int b  = b0 + lj;

    const int t_mid = CRF_CK * c;
    int t1, te;
    float val[4][4];
    if (c == 0) {
        t1 = 1; te = CRF_CK;
        const float* erow0 = em + (size_t)b * (CRF_S * CRF_L);
        UNR for (int mt = 0; mt < 4; ++mt)
          UNR for (int r = 0; r < 4; ++r) {
            int n = mt * 16 + g * 4 + r;
            val[mt][r] = __expf(trans[CRF_BOS * CRF_L + n] + erow0[n]);
          }
    } else {
        t1 = t_mid - CRF_W + 1;
        te = (c == CRF_NC - 1) ? (CRF_S - 1) : (t_mid + CRF_CK);
        UNR for (int mt = 0; mt < 4; ++mt)
          UNR for (int r = 0; r < 4; ++r) val[mt][r] = 1.0f;
    }
    const int NT = (te - t1 + TS) / TS;   // ceil(steps / TS)

    auto issue_tile = [&](int k) {
        const int tt0 = t1 + k * TS;
        const int buf = k & 1;
        int ttl = tt0 + (l >> 4); if (ttl > CRF_S - 1) ttl = CRF_S - 1;
        UNR for (int bb = 0; bb < GRP; ++bb) {
            // pre-swizzled source: slot16 s holds labels 4*(s ^ bb)
            const float* src = em + ((size_t)(b0 + bb) * CRF_S + ttl) * CRF_L
                             + 4 * ((l & 15) ^ bb);
            gload_lds16(src, &em_s[buf][bb][0][0]);
        }
        const float* msrc = mask + (size_t)(b0 + (l & 15)) * CRF_S + ttl;
        gload_lds4(msrc, &mk_s[buf][0][0]);
    };

    float Clog = 0.f, a0 = 0.f;

    issue_tile(0);
    if (NT > 1) issue_tile(1);

    for (int k = 0; k < NT; ++k) {
        const int buf = k & 1;
        const int tt0 = t1 + k * TS;

        if (k + 2 <= NT) {          // tile k+1 stays in flight
            asm volatile("s_waitcnt vmcnt(17)" ::: "memory");
        } else {                    // last tile: drain
            asm volatile("s_waitcnt vmcnt(0)" ::: "memory");
        }
        __builtin_amdgcn_sched_barrier(0);

        // first step's fragments
        f32x4 rc[4]; float mc;
        UNR for (int mt = 0; mt < 4; ++mt)
            rc[mt] = *(const f32x4*)((const char*)&em_s[buf][lj][0][0]
                                     + (((mt * 4 + g) ^ lj) << 4));
        mc = mk_s[buf][0][lj];

        UNR for (int dt = 0; dt < TS; ++dt) {
            const int t = tt0 + dt;
            if (t > te) break;
            f32x4 rn[4]; float mn;
            if (dt + 1 < TS) {      // in-tile prefetch of next step
                UNR for (int mt = 0; mt < 4; ++mt)
                    rn[mt] = *(const f32x4*)((const char*)&em_s[buf][lj][dt + 1][0]
                                             + (((mt * 4 + g) ^ lj) << 4));
                mn = mk_s[buf][dt + 1][lj];
            }
            float ee[16];
            UNR for (int mt = 0; mt < 4; ++mt)
                UNR for (int r = 0; r < 4; ++r)
                    ee[mt * 4 + r] = __expf(rc[mt][r]);

            short8 Bf0, Bf1;
            UNR for (int e = 0; e < 8; ++e) {
                Bf0[e] = (short)f2bf(val[e >> 2][e & 3]);
                Bf1[e] = (short)f2bf(val[2 + (e >> 2)][e & 3]);
            }
            UNR for (int mt = 0; mt < 4; ++mt) {
                f32x4 acc = {0.f, 0.f, 0.f, 0.f};
                acc = __builtin_amdgcn_mfma_f32_16x16x32_bf16(Af[mt][0], Bf0, acc, 0, 0, 0);
                acc = __builtin_amdgcn_mfma_f32_16x16x32_bf16(Af[mt][1], Bf1, acc, 0, 0, 0);
                UNR for (int r = 0; r < 4; ++r) {
                    float nv = acc[r] * ee[mt * 4 + r];
                    val[mt][r] = (mc > 0.5f) ? nv : val[mt][r];
                }
            }
            if ((t & 7) == 0) {
                float rsc = __shfl(val[0][0], l & 15);
                Clog += __logf(rsc);
                float inv = 1.0f / rsc;
                UNR for (int mt = 0; mt < 4; ++mt)
                    UNR for (int r = 0; r < 4; ++r) val[mt][r] *= inv;
            }
            if (t == t_mid) a0 = Clog + __logf(__shfl(val[0][0], l & 15));
            if (dt + 1 < TS) {
                UNR for (int mt = 0; mt < 4; ++mt) rc[mt] = rn[mt];
                mc = mn;
            }
        }
        if (k + 2 < NT) issue_tile(k + 2);
    }

    float a1;
    if (c == CRF_NC - 1) {
        float s = 0.f;
        UNR for (int mt = 0; mt < 4; ++mt)
          UNR for (int r = 0; r < 4; ++r)
            s += val[mt][r] * __expf(trans[(mt * 16 + g * 4 + r) * CRF_L + CRF_EOS]);
        s += __shfl_xor(s, 16);
        s += __shfl_xor(s, 32);
        a1 = Clog + __logf(s);
    } else {
        a1 = Clog + __logf(__shfl(val[0][0], l & 15));
    }
    if (l < 16) atomicAdd(&out[b], a1 - a0);
}

// -------------------- fused kernel (part first, gold behind) ------------
__global__ __launch_bounds__(64) void crf_fused(
    const float* __restrict__ em, const float* __restrict__ trans,
    const int* __restrict__ tags, const float* __restrict__ mask,
    float* __restrict__ out)
{
    __shared__ float em_s[2][GRP][TS][CRF_L];   // 32 KB
    __shared__ float mk_s[2][TS][GRP];          // 512 B
    const int bid = blockIdx.x;
    const int l   = threadIdx.x;
    if (bid < PART_BLOCKS) {
        part_body(bid, l, em, trans, mask, out, em_s, mk_s);
    } else {
        gold_body(bid - PART_BLOCKS, l, em, trans, tags, mask, out);
    }
}

extern "C" void kernel_launch(void* const* d_in, const int* in_sizes, int n_in,
                              void* d_out, int out_size, void* d_ws, size_t ws_size,
                              hipStream_t stream) {
    const float* em    = (const float*)d_in[0];
    const float* trans = (const float*)d_in[1];
    const int*   tags  = (const int*)d_in[2];
    const float* mask  = (const float*)d_in[3];
    float* out  = (float*)d_out;

    hipMemsetAsync(out, 0, CRF_B * sizeof(float), stream);
    crf_fused<<<PART_BLOCKS + CRF_B, 64, 0, stream>>>(em, trans, tags, mask, out);
}